// Round 1
// 13360.681 us; speedup vs baseline: 2.2176x; 2.2176x over previous
//
#include <hip/hip_runtime.h>
#include <stdint.h>

// ============================================================================
// Persistent-RNN kernel for RecBlock: 2048 sequential steps, one device-wide
// barrier per step (BN batch statistics are the only cross-wg coupling).
//
// Partition: 128 persistent workgroups = 16 row-groups (16 batch rows each)
//            x 8 col-groups (32 hidden cols each; 16 output cols each).
// Weights (W_ih slice, W_ho slice) live in LDS for the whole kernel as
// bf16 hi/lo pairs; GEMMs run on v_mfma_f32_16x16x32_bf16 with a 3-term
// hi/lo expansion (hi*hi + hi*lo + lo*hi) for near-fp32 accuracy.
//
// Sync redesign vs previous version (which spent ~14 us/step):
//  * All cross-wg exchange data (zbuf, partials, flags) uses agent-scope
//    relaxed atomics -> global_{load,store} ... sc1, coherent at the MALL.
//    NO __threadfence: no per-step buffer_wbl2 (L2 writeback) and no
//    buffer_inv (L2 invalidate). X / gamma / beta stay cached in L2.
//    Release ordering is free: __syncthreads() drains vmcnt(0) before
//    s_barrier, which for sc1 stores means globally visible.
//  * Distributed flag barrier: each wg stores flags[bid]=t+1 (one sc1
//    store, monotonic -> no reset, parity-safe); 128 threads poll the 128
//    flags in parallel. Replaces 128 serialized same-line atomic RMWs.
//  * zbuf reads issued before partials reads so the stats compute hides
//    under the zbuf MALL round trip (single latency, not two).
//  * gamma/beta hoisted to registers; separate LDS region for the output
//    reduction drops one __syncthreads per step.
//
// b_ih is omitted: a per-column constant cancels exactly in (z - mean(z)).
// ============================================================================

#define S_LEN 2048
#define BATCH 256
#define NIN   128
#define HID   256
#define NOUT  128

#define NBLK  128   // 16 row-groups x 8 col-groups (1 block/CU by LDS)
#define NTHR  256   // 4 waves
#define NR    16    // batch rows per wg
#define NC    32    // z columns per wg
#define NO    16    // output columns per wg

#define HXW   392   // padded k-stride (shorts) for hx and W_ih slices (384+8)
#define WHOW  264   // padded k-stride (shorts) for W_ho slice (256+8)

typedef short short8  __attribute__((ext_vector_type(8)));
typedef float float4v __attribute__((ext_vector_type(4)));

// LDS layout (in shorts for the bf16 region, floats after)
#define HXHI_OFF  0
#define HXLO_OFF  (16*HXW)
#define WHI_OFF   (2*16*HXW)
#define WLO_OFF   (2*16*HXW + 32*HXW)
#define WHOHI_OFF (2*16*HXW + 2*32*HXW)
#define WHOLO_OFF (WHOHI_OFF + 16*WHOW)
#define SHORTS_TOTAL (WHOLO_OFF + 16*WHOW)      // 46080 shorts = 92160 B
#define RED_F 1088                               // 4 x 16 x 17 floats
#define SMEM_BYTES (SHORTS_TOTAL*2 + (2*RED_F + 256 + 256 + 16)*4)  // 102976 B

// workspace layout (bytes):
//   0      : flags, 128 entries, stride 128 B (monotonic step stamps)
//   16384  : partials  2 x 16 x 256 float2  (per parity, per rowg: sum,sumsq)
//   81920  : zbuf      2 x 256 x 256 floats (per parity, pre-BN z)
// total ~592 KB

#define MFMA(a,b,c) __builtin_amdgcn_mfma_f32_16x16x32_bf16(a,b,c,0,0,0)

#define AG_ST(p, v) __hip_atomic_store((p), (v), __ATOMIC_RELAXED, __HIP_MEMORY_SCOPE_AGENT)
#define AG_LD(p)    __hip_atomic_load((p), __ATOMIC_RELAXED, __HIP_MEMORY_SCOPE_AGENT)

__device__ __forceinline__ short f2bf(float f) {
  unsigned u = __float_as_uint(f);
  unsigned r = (u + 0x7fffu + ((u >> 16) & 1u)) >> 16;  // RNE
  return (short)r;
}
__device__ __forceinline__ float bf2f(short s) {
  return __uint_as_float(((unsigned)(unsigned short)s) << 16);
}
__device__ __forceinline__ float gelu_f(float x) {
  return 0.5f * x * (1.0f + erff(x * 0.70710678118654752f));
}

// stage X[:, t, :] slice (16 rows x 128) into hx bf16 hi/lo
__device__ __forceinline__ void stage_x(const float* __restrict__ X,
                                        short* hx_hi, short* hx_lo,
                                        int r0, int t, int tid) {
  int row = tid >> 4;           // 0..15
  int k0  = (tid & 15) * 8;     // 0..120
  const float* xp = X + ((size_t)(r0 + row) * S_LEN + t) * NIN + k0;
  float4v a = *(const float4v*)xp;
  float4v b = *(const float4v*)(xp + 4);
  short8 hi, lo;
#pragma unroll
  for (int j = 0; j < 4; ++j) {
    short h1 = f2bf(a[j]); hi[j] = h1; lo[j] = f2bf(a[j] - bf2f(h1));
  }
#pragma unroll
  for (int j = 0; j < 4; ++j) {
    short h1 = f2bf(b[j]); hi[4+j] = h1; lo[4+j] = f2bf(b[j] - bf2f(h1));
  }
  *(short8*)(hx_hi + row*HXW + k0) = hi;
  *(short8*)(hx_lo + row*HXW + k0) = lo;
}

__global__ void init_flags(unsigned* flags) {
  // agent-scope stores so the zeros land at the MALL (where rec_kernel's
  // sc1 polls read), not as dirty lines in one XCD's L2.
  AG_ST(flags + (size_t)threadIdx.x * 32, 0u);
}

__global__ void __launch_bounds__(NTHR, 1)
rec_kernel(const float* __restrict__ X, const float* __restrict__ W_ih,
           const float* __restrict__ W_ho, const float* __restrict__ b_ho,
           const float* __restrict__ gamma, const float* __restrict__ beta,
           float* __restrict__ out, unsigned* __restrict__ flags,
           float* __restrict__ part, float* __restrict__ zbuf)
{
  extern __shared__ char smemraw[];
  short* sh      = (short*)smemraw;
  short* hx_hi   = sh + HXHI_OFF;   // [16][HXW]  k: 0..127 = x_t, 128..383 = h_t
  short* hx_lo   = sh + HXLO_OFF;
  short* w_hi    = sh + WHI_OFF;    // [32][HXW]  W_ih rows c0..c0+31
  short* w_lo    = sh + WLO_OFF;
  short* who_hi  = sh + WHOHI_OFF;  // [16][WHOW] W_ho rows oc0..oc0+15
  short* who_lo  = sh + WHOLO_OFF;
  float* red     = (float*)(sh + SHORTS_TOTAL); // [2][16][17]x2 z-GEMM reduce
  float* red2    = red + RED_F;     // [4][16][17] out-GEMM reduce (own region)
  float* sscale  = red2 + RED_F;    // [256] BN scale per column
  float* sshift  = sscale + 256;    // [256] BN shift per column
  float* sbho    = sshift + 256;    // [16]

  const int tid   = threadIdx.x;
  const int rowg  = blockIdx.x >> 3;   // 0..15
  const int colg  = blockIdx.x & 7;    // 0..7
  const int r0    = rowg * NR;
  const int c0    = colg * NC;
  const int oc0   = colg * NO;
  const int wv    = tid >> 6;          // wave 0..3
  const int lane  = tid & 63;
  const int nn    = lane & 15;         // MFMA m / n index
  const int quad  = lane >> 4;         // MFMA k-group / row-group
  const int sub   = wv >> 1;           // z col-subtile 0/1
  const int khalf = wv & 1;            // K half for z-GEMM

  // ---- one-time init: stage weight slices into LDS as bf16 hi/lo ----
  for (int idx = tid; idx < NC * 384; idx += NTHR) {
    int r = idx / 384, j = idx % 384;
    float w = W_ih[(size_t)(c0 + r) * 384 + j];
    short hi = f2bf(w);
    w_hi[r*HXW + j] = hi;
    w_lo[r*HXW + j] = f2bf(w - bf2f(hi));
  }
  for (int idx = tid; idx < NO * 256; idx += NTHR) {
    int r = idx / 256, j = idx % 256;
    float w = W_ho[(size_t)(oc0 + r) * 256 + j];
    short hi = f2bf(w);
    who_hi[r*WHOW + j] = hi;
    who_lo[r*WHOW + j] = f2bf(w - bf2f(hi));
  }
  if (tid < NO) sbho[tid] = b_ho[oc0 + tid];
  // h0 = 0: zero the h region of hx (k in [128, 392))
  for (int idx = tid; idx < 16 * 33; idx += NTHR) {
    int row = idx / 33, k0 = 128 + (idx % 33) * 8;
    short8 z8 = {0,0,0,0,0,0,0,0};
    *(short8*)(hx_hi + row*HXW + k0) = z8;
    *(short8*)(hx_lo + row*HXW + k0) = z8;
  }
  stage_x(X, hx_hi, hx_lo, r0, 0, tid);

  const float g_gamma = gamma[tid];   // loop-invariant (tid = BN column)
  const float g_beta  = beta[tid];
  __syncthreads();

  for (int t = 0; t < S_LEN; ++t) {
    const int p = t & 1;
    float* partp = part + p * (16 * 512);          // 16 rowg x 256 col x float2
    float* zbp   = zbuf + p * (BATCH * HID);

    // ---- z-GEMM: z[r0..r0+15][c0+sub*16 .. +16) over K half ----
    float4v acc = {0.f, 0.f, 0.f, 0.f};
    {
      const short* arow_hi = hx_hi + nn*HXW;             // A row m = nn
      const short* arow_lo = hx_lo + nn*HXW;
      const short* brow_hi = w_hi + (sub*16 + nn)*HXW;   // B col n = nn
      const short* brow_lo = w_lo + (sub*16 + nn)*HXW;
      int kb = khalf*192 + quad*8;
#pragma unroll
      for (int ks = 0; ks < 6; ++ks) {
        short8 ah = *(const short8*)(arow_hi + kb);
        short8 al = *(const short8*)(arow_lo + kb);
        short8 bh = *(const short8*)(brow_hi + kb);
        short8 bl = *(const short8*)(brow_lo + kb);
        acc = MFMA(ah, bh, acc);
        acc = MFMA(ah, bl, acc);
        acc = MFMA(al, bh, acc);
        kb += 32;
      }
    }
    if (khalf == 1) {   // publish K-half-1 partial for cross-wave reduce
#pragma unroll
      for (int i = 0; i < 4; ++i) red[sub*272 + (quad*4 + i)*17 + nn] = acc[i];
    }
    __syncthreads();  // S1
    if (khalf == 0) {
#pragma unroll
      for (int i = 0; i < 4; ++i) acc[i] += red[sub*272 + (quad*4 + i)*17 + nn];
      // store pre-BN z tile: agent-scope (sc1) -> coherent at MALL, no fence
      float* zb = zbp + (size_t)(r0 + quad*4) * HID + (c0 + sub*16 + nn);
#pragma unroll
      for (int i = 0; i < 4; ++i) AG_ST(zb + i*HID, acc[i]);
      // per-column partial sums over our 16 rows
      float s = acc[0] + acc[1] + acc[2] + acc[3];
      float q = acc[0]*acc[0] + acc[1]*acc[1] + acc[2]*acc[2] + acc[3]*acc[3];
      s += __shfl_down(s, 32);  q += __shfl_down(q, 32);
      s += __shfl_down(s, 16);  q += __shfl_down(q, 16);
      if (lane < 16) {
        int c = c0 + sub*16 + lane;
        unsigned long long pv = ((unsigned long long)__float_as_uint(q) << 32)
                              | (unsigned long long)__float_as_uint(s);
        AG_ST((unsigned long long*)partp + (rowg*256 + c), pv);
      }
    }
    // S2: compiler drains vmcnt(0) before s_barrier -> all waves' sc1 stores
    // are at the coherence point when any thread proceeds. This IS the
    // release; no buffer_wbl2 needed since nothing dirty-in-L2 is exchanged.
    __syncthreads();

    // ---- distributed flag barrier (one sc1 store, parallel polls) ----
    if (tid == 0)
      AG_ST(flags + (size_t)blockIdx.x * 32, (unsigned)(t + 1));
    // overlap barrier latency: prefetch next X slice into hx x-region
    if (t + 1 < S_LEN) stage_x(X, hx_hi, hx_lo, r0, t + 1, tid);
    if (tid < NBLK) {
      const unsigned* fp = flags + (size_t)tid * 32;
      while (AG_LD(fp) < (unsigned)(t + 1)) __builtin_amdgcn_s_sleep(1);
    }
    __syncthreads();  // S3

    // ---- issue zbuf reads early (independent of stats) ----
    const int zrow = tid >> 4;            // 0..15 (row within our 16)
    const int zcb  = (tid & 15) * 16;     // 16 contiguous cols per thread
    unsigned long long zt[8];
    {
      const unsigned long long* zp = (const unsigned long long*)
          (zbp + (size_t)(r0 + zrow) * HID + zcb);
#pragma unroll
      for (int j = 0; j < 8; ++j) zt[j] = AG_LD(zp + j);
    }

    // ---- stats: reduce all 16 row-group partials (this thread = col tid) ----
    {
      const unsigned long long* pp = (const unsigned long long*)partp + tid;
      unsigned long long pv[16];
#pragma unroll
      for (int rg = 0; rg < 16; ++rg) pv[rg] = AG_LD(pp + rg*256);
      float sA = 0.f, sB = 0.f;
#pragma unroll
      for (int rg = 0; rg < 16; ++rg) {
        sA += __uint_as_float((unsigned)pv[rg]);
        sB += __uint_as_float((unsigned)(pv[rg] >> 32));
      }
      float mu   = sA * (1.0f/256.0f);
      float var  = sB * (1.0f/256.0f) - mu*mu;    // biased, matches BN training
      float rstd = rsqrtf(var + 1e-5f);
      float g    = g_gamma * rstd;
      sscale[tid] = g;
      sshift[tid] = g_beta - mu * g;
    }
    __syncthreads();  // S4

    // ---- reconstruct h_{t+1} for our 16 full rows: BN + exact GELU ----
    {
      short hb[16], lb[16];
#pragma unroll
      for (int j = 0; j < 16; ++j) {
        float z  = __uint_as_float((unsigned)(zt[j >> 1] >> ((j & 1) * 32)));
        float zn = z * sscale[zcb + j] + sshift[zcb + j];
        float h  = gelu_f(zn);
        short hh = f2bf(h);
        hb[j] = hh; lb[j] = f2bf(h - bf2f(hh));
      }
      short* dh = hx_hi + zrow*HXW + 128 + zcb;
      short* dl = hx_lo + zrow*HXW + 128 + zcb;
      *(short8*)(dh)     = *(short8*)(hb);
      *(short8*)(dh + 8) = *(short8*)(hb + 8);
      *(short8*)(dl)     = *(short8*)(lb);
      *(short8*)(dl + 8) = *(short8*)(lb + 8);
    }
    __syncthreads();  // S5

    // ---- output GEMM: o[r0..r0+15][oc0..oc0+15], K=256 split over 4 waves ----
    {
      float4v oacc = {0.f, 0.f, 0.f, 0.f};
      const short* arow_hi = hx_hi + nn*HXW + 128;
      const short* arow_lo = hx_lo + nn*HXW + 128;
      const short* brow_hi = who_hi + nn*WHOW;
      const short* brow_lo = who_lo + nn*WHOW;
      int kb = wv*64 + quad*8;
#pragma unroll
      for (int ks = 0; ks < 2; ++ks) {
        short8 ah = *(const short8*)(arow_hi + kb);
        short8 al = *(const short8*)(arow_lo + kb);
        short8 bh = *(const short8*)(brow_hi + kb);
        short8 bl = *(const short8*)(brow_lo + kb);
        oacc = MFMA(ah, bh, oacc);
        oacc = MFMA(ah, bl, oacc);
        oacc = MFMA(al, bh, oacc);
        kb += 32;
      }
#pragma unroll
      for (int i = 0; i < 4; ++i) red2[wv*272 + (quad*4 + i)*17 + nn] = oacc[i];
    }
    __syncthreads();  // S6
    {
      int row = tid >> 4, col = tid & 15;
      float v = red2[0*272 + row*17 + col] + red2[1*272 + row*17 + col]
              + red2[2*272 + row*17 + col] + red2[3*272 + row*17 + col]
              + sbho[col];
      out[((size_t)(r0 + row) * S_LEN + t) * NOUT + oc0 + col] = gelu_f(v);
    }
    // no S7 needed: next iteration's z-phase uses red (not red2), hx h-region
    // writes are protected by S5, and next stage_x is after next S2.
  }
}

extern "C" void kernel_launch(void* const* d_in, const int* in_sizes, int n_in,
                              void* d_out, int out_size, void* d_ws, size_t ws_size,
                              hipStream_t stream) {
  const float* X     = (const float*)d_in[0];
  const float* W_ih  = (const float*)d_in[1];
  // d_in[2] = b_ih: unused (per-column constant cancels exactly in BatchNorm)
  const float* W_ho  = (const float*)d_in[3];
  const float* b_ho  = (const float*)d_in[4];
  const float* gamma = (const float*)d_in[5];
  const float* beta  = (const float*)d_in[6];
  float* out = (float*)d_out;

  unsigned* flags = (unsigned*)d_ws;                  // 16 KB (128 x 128 B)
  float* part = (float*)((char*)d_ws + 16384);        // 64 KB (2 parities)
  float* zbuf = part + 2 * 16 * 512;                  // 512 KB (2 parities)

  init_flags<<<dim3(1), dim3(NBLK), 0, stream>>>(flags);

  hipFuncSetAttribute((const void*)rec_kernel,
                      hipFuncAttributeMaxDynamicSharedMemorySize, SMEM_BYTES);

  // 128 blocks, 1 per CU (LDS-limited) on a 256-CU idle device -> all
  // co-resident; distributed monotonic flag barrier handles grid sync.
  rec_kernel<<<dim3(NBLK), dim3(NTHR), SMEM_BYTES, stream>>>(
      X, W_ih, W_ho, b_ho, gamma, beta, out, flags, part, zbuf);
}